// Round 2
// baseline (875.067 us; speedup 1.0000x reference)
//
#include <hip/hip_runtime.h>
#include <hip/hip_bf16.h>
#include <cstdint>
#include <cstddef>

// x[512,4096] fp32 ; gate/up codes [11008,4096] i32 ; down codes [4096,11008] i32
// absmax blocks of 64 along K ; out [512,4096] fp32
// Pipeline: cast x->bf16 ; gate GEMM -> g(bf16) ; up GEMM + silu(g)*u -> h(bf16) ;
// down GEMM split-K=4 with fp32 atomics -> out.

using float4v = __attribute__((ext_vector_type(4))) float;
using short8  = __attribute__((ext_vector_type(8))) short;

__constant__ float NF4TAB[16] = {
  -1.0f, -0.6961928009986877f, -0.5250730514526367f, -0.39491748809814453f,
  -0.28444138169288635f, -0.18477343022823334f, -0.09105003625154495f, 0.0f,
  0.07958029955625534f, 0.16093020141124725f, 0.24611230194568634f,
  0.33791524171829224f, 0.44070982933044434f, 0.5626170039176941f,
  0.7229568362236023f, 1.0f };

__device__ __forceinline__ unsigned short f2bf(float f) {
  unsigned u = __float_as_uint(f);
  u += 0x7fffu + ((u >> 16) & 1u);        // RNE
  return (unsigned short)(u >> 16);
}
__device__ __forceinline__ float bf2f(unsigned short b) {
  return __uint_as_float(((unsigned)b) << 16);
}
__device__ __forceinline__ void async16(const void* g, void* l) {
  __builtin_amdgcn_global_load_lds(
      (const __attribute__((address_space(1))) void*)g,
      (__attribute__((address_space(3))) void*)l, 16, 0, 0);
}

// C[512 x N] = A[512 x K](bf16) * dequant(codes[N x K])^T
// Block tile 128(M) x 64(N), BK=64, 256 thr (4 waves, 2x2 wave grid, wave tile 64x32).
// Double-buffered LDS, single barrier per K-iter.
// EPI 0: bf16 C -> outB.  EPI 1: silu(gIn)*C -> outB.  EPI 2: fp32 atomicAdd -> outF.
template <int EPI>
__global__ __launch_bounds__(256, 3) void gemm_nf4(
    const unsigned short* __restrict__ A,
    const int* __restrict__ codes,
    const float* __restrict__ absmax,
    float* __restrict__ outF,
    unsigned short* __restrict__ outB,
    const unsigned short* __restrict__ gIn,
    int N, int K, int Kc, int Mtiles, int Ntiles)
{
  __shared__ unsigned short Abuf[2][128 * 64];  // 16 KB x2, XOR-swizzled 16B chunks
  __shared__ unsigned short Bbuf[2][64 * 72];   // 9 KB x2, +8 bf16 row pad
  __shared__ float tab[16];

  const int tid  = threadIdx.x;
  const int lane = tid & 63;
  const int wave = tid >> 6;
  const int wm   = wave & 1;     // M half (64 rows)
  const int wn   = wave >> 1;    // N half (32 cols)

  if (tid < 16) tab[tid] = NF4TAB[tid];

  const int bid = blockIdx.x;
  const int mt  = bid % Mtiles;
  const int r1  = bid / Mtiles;
  const int nt  = r1 % Ntiles;
  const int ks  = r1 / Ntiles;

  const int row0 = mt * 128;
  const int col0 = nt * 64;
  const int k0   = ks * Kc;
  const int nk   = Kc >> 6;

  // A async staging: wave stages 32 rows (4 calls x 8 rows); XOR chunk swizzle
  const int arow = lane >> 3;
  const int achk = (lane & 7) ^ arow;
  const unsigned short* aSrc =
      A + (size_t)(row0 + wave * 32 + arow) * K + k0 + achk * 8;

  // B staging: thread -> (row bn, 16-code quarter bq); coalesced int4 loads
  const int bn = tid >> 2;
  const int bq = tid & 3;
  const int* cSrc = codes + (size_t)(col0 + bn) * K + k0;
  const float* amSrc = absmax + (size_t)(col0 + bn) * (K >> 6) + (k0 >> 6);

  float4v acc[4][2];
  {
    float4v z = {0.f, 0.f, 0.f, 0.f};
    #pragma unroll
    for (int i = 0; i < 4; ++i)
      #pragma unroll
      for (int j = 0; j < 2; ++j) acc[i][j] = z;
  }

#define STAGEA(kt, buf)                                                         \
  { _Pragma("unroll")                                                           \
    for (int j = 0; j < 4; ++j)                                                 \
      async16(aSrc + (size_t)j * 8 * K + (size_t)(kt) * 64,                     \
              &Abuf[buf][(wave * 32 + j * 8) * 64]); }

#define LOADC(kt)                                                               \
  { const int4* p = (const int4*)(cSrc + (kt) * 64);                            \
    cr[0] = p[bq]; cr[1] = p[4 + bq]; cr[2] = p[8 + bq]; cr[3] = p[12 + bq];    \
    am = amSrc[kt]; }

#define DEQB(buf)                                                               \
  { _Pragma("unroll")                                                           \
    for (int i = 0; i < 4; ++i) {                                               \
      ushort4 w;                                                                \
      w.x = f2bf(tab[cr[i].x] * am); w.y = f2bf(tab[cr[i].y] * am);             \
      w.z = f2bf(tab[cr[i].z] * am); w.w = f2bf(tab[cr[i].w] * am);             \
      *(ushort4*)&Bbuf[buf][bn * 72 + i * 16 + bq * 4] = w; } }

  __syncthreads();   // tab visible before any dequant

  int4 cr[4]; float am;
  STAGEA(0, 0);
  LOADC(0);
  DEQB(0);
  if (nk > 1) LOADC(1);
  __syncthreads();   // drains A0 (vmcnt), B0 visible

  for (int kt = 0; kt < nk; ++kt) {
    const int p = kt & 1, np = p ^ 1;
    if (kt + 1 < nk) {
      STAGEA(kt + 1, np);          // async into idle buffer
      DEQB(np);                    // codes(kt+1) from regs -> idle buffer
      if (kt + 2 < nk) LOADC(kt + 2);  // prefetch next codes (in flight over compute)
    }
    // compute tile kt
    #pragma unroll
    for (int kk = 0; kk < 2; ++kk) {
      short8 af[4], bfr[2];
      #pragma unroll
      for (int i = 0; i < 4; ++i) {
        const int row_l = wm * 64 + i * 16 + (lane & 15);
        const int phys  = (kk * 4 + (lane >> 4)) ^ (row_l & 7);
        af[i] = *(const short8*)&Abuf[p][row_l * 64 + phys * 8];
      }
      #pragma unroll
      for (int j = 0; j < 2; ++j) {
        const int n_l = wn * 32 + j * 16 + (lane & 15);
        bfr[j] = *(const short8*)&Bbuf[p][n_l * 72 + kk * 32 + (lane >> 4) * 8];
      }
      #pragma unroll
      for (int i = 0; i < 4; ++i)
        #pragma unroll
        for (int j = 0; j < 2; ++j)
          acc[i][j] = __builtin_amdgcn_mfma_f32_16x16x32_bf16(af[i], bfr[j], acc[i][j], 0, 0, 0);
    }
    __syncthreads();   // protects both buffers + drains async/prefetch
  }

  // epilogue. C/D map: col = lane&15, row = (lane>>4)*4 + reg
  const int ccol0 = col0 + wn * 32 + (lane & 15);
  const int crow0 = row0 + wm * 64 + ((lane >> 4) << 2);
  #pragma unroll
  for (int i = 0; i < 4; ++i) {
    #pragma unroll
    for (int j = 0; j < 2; ++j) {
      #pragma unroll
      for (int r = 0; r < 4; ++r) {
        const size_t idx = (size_t)(crow0 + i * 16 + r) * N + (ccol0 + j * 16);
        if (EPI == 2) {
          atomicAdd(&outF[idx], acc[i][j][r]);
        } else if (EPI == 0) {
          outB[idx] = f2bf(acc[i][j][r]);
        } else {
          const float gv = bf2f(gIn[idx]);
          const float s  = gv / (1.f + __expf(-gv));
          outB[idx] = f2bf(s * acc[i][j][r]);
        }
      }
    }
  }
#undef STAGEA
#undef LOADC
#undef DEQB
}

__global__ void cast_bf16_kernel(const float* __restrict__ x,
                                 unsigned short* __restrict__ xb, int n4) {
  int i = blockIdx.x * blockDim.x + threadIdx.x;
  if (i < n4) {
    float4 v = ((const float4*)x)[i];
    ushort4 o;
    o.x = f2bf(v.x); o.y = f2bf(v.y); o.z = f2bf(v.z); o.w = f2bf(v.w);
    ((ushort4*)xb)[i] = o;
  }
}

extern "C" void kernel_launch(void* const* d_in, const int* in_sizes, int n_in,
                              void* d_out, int out_size, void* d_ws, size_t ws_size,
                              hipStream_t stream)
{
  (void)in_sizes; (void)n_in; (void)ws_size;
  const float* x            = (const float*)d_in[0];
  const int*   gate_codes   = (const int*)d_in[1];
  const float* gate_absmax  = (const float*)d_in[2];
  const int*   up_codes     = (const int*)d_in[3];
  const float* up_absmax    = (const float*)d_in[4];
  const int*   down_codes   = (const int*)d_in[5];
  const float* down_absmax  = (const float*)d_in[6];
  float* out = (float*)d_out;

  unsigned short* xb = (unsigned short*)d_ws;                   // 4 MB
  unsigned short* g  = xb + (size_t)512 * 4096;                 // 11.3 MB
  unsigned short* h  = g  + (size_t)512 * 11008;                // 11.3 MB

  hipMemsetAsync(d_out, 0, (size_t)out_size * sizeof(float), stream);

  cast_bf16_kernel<<<2048, 256, 0, stream>>>(x, xb, (512 * 4096) / 4);

  // gate: [512,11008] <- xb * Wg^T.   grid = 4 Mtiles * 172 Ntiles
  gemm_nf4<0><<<688, 256, 0, stream>>>(xb, gate_codes, gate_absmax,
                                       nullptr, g, nullptr,
                                       11008, 4096, 4096, 4, 172);
  // up + SwiGLU: h = silu(g) * (xb * Wu^T)
  gemm_nf4<1><<<688, 256, 0, stream>>>(xb, up_codes, up_absmax,
                                       nullptr, h, g,
                                       11008, 4096, 4096, 4, 172);
  // down: out += h * Wd^T, split-K=4.  grid = 4 * 64 * 4 = 1024
  gemm_nf4<2><<<1024, 256, 0, stream>>>(h, down_codes, down_absmax,
                                        out, nullptr, nullptr,
                                        4096, 11008, 2752, 4, 64);
}

// Round 3
// 864.840 us; speedup vs baseline: 1.0118x; 1.0118x over previous
//
#include <hip/hip_runtime.h>
#include <hip/hip_fp16.h>
#include <cstdint>
#include <cstddef>

// x[512,4096] fp32 ; gate/up codes [11008,4096] i32 ; down codes [4096,11008] i32
// absmax blocks of 64 along K ; out [512,4096] fp32
// R3 structure: A direct-from-L2 register fragments (no A-LDS, no global_load_lds),
// codes prefetched 2 iters ahead in regs, B dequant via 256-entry packed f16 pair
// table, double-buffered B LDS, one barrier/iter. gate+up fused in one dispatch
// (256-row M-tiles keep code duplication at the measured-safe 2x).

using float4v = __attribute__((ext_vector_type(4))) float;
using half8   = __attribute__((ext_vector_type(8))) _Float16;

__constant__ float NF4TAB[16] = {
  -1.0f, -0.6961928009986877f, -0.5250730514526367f, -0.39491748809814453f,
  -0.28444138169288635f, -0.18477343022823334f, -0.09105003625154495f, 0.0f,
  0.07958029955625534f, 0.16093020141124725f, 0.24611230194568634f,
  0.33791524171829224f, 0.44070982933044434f, 0.5626170039176941f,
  0.7229568362236023f, 1.0f };

// C[512 x N] = A[512 x K](f16) * dequant(codes[N x K])^T
// Block 256M x 64N, BK=64, 4 waves, wave tile 64x64 (4x4 MFMA 16x16x32 f16).
// ATOMIC=false: two matrices in one dispatch (r2 selects gate/up), f16 stores.
// ATOMIC=true : split-K (r2 = K-chunk), fp32 atomicAdd into outF.
template <bool ATOMIC>
__global__ __launch_bounds__(256, 2) void gemm_nf4(
    const __half* __restrict__ Ag,
    const int* __restrict__ c0, const float* __restrict__ am0,
    const int* __restrict__ c1, const float* __restrict__ am1,
    __half* __restrict__ o0, __half* __restrict__ o1,
    float* __restrict__ outF,
    int N, int K, int Kc, int Ntiles)
{
  __shared__ __half    Bb[2][64 * 72];   // 18 KB double-buffered B tile, pad 72
  __shared__ unsigned  ptab[256];        // packed f16 pair table: {tab[lo], tab[hi]}

  const int tid  = threadIdx.x;
  const int lane = tid & 63;
  const int wave = tid >> 6;

  {
    __half2 pr = __floats2half2_rn(NF4TAB[tid & 15], NF4TAB[tid >> 4]);
    ptab[tid] = *(const unsigned*)&pr;
  }

  const int bid = blockIdx.x;
  const int mt  = bid & 1;               // 2 M-tiles of 256 rows
  const int r   = bid >> 1;
  const int nt  = r % Ntiles;
  const int r2  = r / Ntiles;            // mat (gate/up) or K-chunk

  const int k0 = ATOMIC ? r2 * Kc : 0;
  const int nk = Kc >> 6;
  const int* codes   = (!ATOMIC && r2) ? c1 : c0;
  const float* amax  = (!ATOMIC && r2) ? am1 : am0;
  __half* outH       = (!ATOMIC && r2) ? o1 : o0;

  const int row0 = mt * 256;
  const int col0 = nt * 64;
  const int Kb   = K >> 6;               // absmax row stride

  // code staging: thread -> (row bn, quarter bq); per-instr 64B clusters
  const int bn = tid >> 2;
  const int bq = tid & 3;
  const int4* cSrc   = (const int4*)(codes + (size_t)(col0 + bn) * K + k0);
  const float* amSrc = amax + (size_t)(col0 + bn) * Kb + (k0 >> 6);

  // A-fragment base: wave owns 64 M-rows; frag i: rows +i*16; lane m=lane&15,
  // k = (lane>>4)*8 + j  (per-wave: 16 rows x 64B contiguous -> coalesced)
  const __half* aBase = Ag + (size_t)(row0 + wave * 64 + (lane & 15)) * K
                           + k0 + ((lane >> 4) << 3);

  float4v acc[4][4];
  {
    float4v z = {0.f, 0.f, 0.f, 0.f};
    #pragma unroll
    for (int i = 0; i < 4; ++i)
      #pragma unroll
      for (int j = 0; j < 4; ++j) acc[i][j] = z;
  }

  int4  cr[2][4];
  float amr[2];
  half8 apf[2][4];

#define LOADC(S, KT)                                                            \
  { const int4* _p = cSrc + (KT) * 16;                                          \
    cr[S][0] = _p[bq];      cr[S][1] = _p[4 + bq];                              \
    cr[S][2] = _p[8 + bq];  cr[S][3] = _p[12 + bq];                             \
    amr[S] = amSrc[KT]; }

#define DEQB(BUFI, S)                                                           \
  { const __half _ah = __float2half(amr[S]);                                    \
    const __half2 _am2 = __half2{_ah, _ah};                                     \
    _Pragma("unroll")                                                           \
    for (int _i = 0; _i < 4; ++_i) {                                            \
      unsigned _w0 = ptab[cr[S][_i].x | (cr[S][_i].y << 4)];                    \
      unsigned _w1 = ptab[cr[S][_i].z | (cr[S][_i].w << 4)];                    \
      __half2 _p0 = __hmul2(*(const __half2*)&_w0, _am2);                       \
      __half2 _p1 = __hmul2(*(const __half2*)&_w1, _am2);                       \
      uint2 _wv; _wv.x = *(const unsigned*)&_p0; _wv.y = *(const unsigned*)&_p1;\
      *(uint2*)&Bb[BUFI][bn * 72 + _i * 16 + bq * 4] = _wv; } }

#define LOADA(DST, KT, KK)                                                      \
  { _Pragma("unroll")                                                           \
    for (int _i = 0; _i < 4; ++_i)                                              \
      DST[_i] = *(const half8*)(aBase + (size_t)_i * 16 * K + (KT) * 64 + (KK) * 32); }

  // prologue
  LOADC(0, 0);
  if (nk > 1) LOADC(1, 1);
  __syncthreads();                 // ptab visible
  DEQB(0, 0);
  if (nk > 2) LOADC(0, 2);
  LOADA(apf[0], 0, 0);
  __syncthreads();                 // Bb[0] visible

#define BODY(KT, S)                                                             \
  { const int _np = (S) ^ 1;                                                    \
    if ((KT) + 1 < nk) {                                                        \
      DEQB(_np, _np);              /* codes(KT+1), aged 2 iters */              \
      if ((KT) + 3 < nk) LOADC(_np, (KT) + 3);                                  \
      LOADA(apf[_np], (KT) + 1, 0);                                             \
    }                                                                           \
    half8 a1[4];                                                                \
    LOADA(a1, KT, 1);              /* kk=1 frags; wait hidden under kk=0 MFMA */\
    half8 bf[4];                                                                \
    _Pragma("unroll")                                                           \
    for (int _j = 0; _j < 4; ++_j)                                              \
      bf[_j] = *(const half8*)&Bb[S][(_j * 16 + (lane & 15)) * 72 + ((lane >> 4) << 3)]; \
    _Pragma("unroll")                                                           \
    for (int _i = 0; _i < 4; ++_i)                                              \
      _Pragma("unroll")                                                         \
      for (int _j = 0; _j < 4; ++_j)                                            \
        acc[_i][_j] = __builtin_amdgcn_mfma_f32_16x16x32_f16(apf[S][_i], bf[_j], acc[_i][_j], 0, 0, 0); \
    _Pragma("unroll")                                                           \
    for (int _j = 0; _j < 4; ++_j)                                              \
      bf[_j] = *(const half8*)&Bb[S][(_j * 16 + (lane & 15)) * 72 + 32 + ((lane >> 4) << 3)]; \
    _Pragma("unroll")                                                           \
    for (int _i = 0; _i < 4; ++_i)                                              \
      _Pragma("unroll")                                                         \
      for (int _j = 0; _j < 4; ++_j)                                            \
        acc[_i][_j] = __builtin_amdgcn_mfma_f32_16x16x32_f16(a1[_i], bf[_j], acc[_i][_j], 0, 0, 0); \
    __syncthreads(); }

  int kt = 0;
  while (kt + 2 <= nk) { BODY(kt, 0); BODY(kt + 1, 1); kt += 2; }
  if (kt < nk) BODY(kt, 0);        // odd nk tail (down: nk=43), parity 0

  // epilogue. C/D map (verified): col = lane&15, row = (lane>>4)*4 + reg
  const int ccol0 = col0 + (lane & 15);
  const int crow0 = row0 + wave * 64 + ((lane >> 4) << 2);
  #pragma unroll
  for (int i = 0; i < 4; ++i)
    #pragma unroll
    for (int j = 0; j < 4; ++j)
      #pragma unroll
      for (int rr = 0; rr < 4; ++rr) {
        const size_t idx = (size_t)(crow0 + i * 16 + rr) * N + (ccol0 + j * 16);
        if (ATOMIC) atomicAdd(&outF[idx], acc[i][j][rr]);
        else        outH[idx] = __float2half(acc[i][j][rr]);
      }
#undef LOADC
#undef DEQB
#undef LOADA
#undef BODY
}

__global__ void cast_f16_kernel(const float* __restrict__ x,
                                __half* __restrict__ xh, int n4) {
  int i = blockIdx.x * blockDim.x + threadIdx.x;
  if (i < n4) {
    float4 v = ((const float4*)x)[i];
    __half2 h0 = __floats2half2_rn(v.x, v.y);
    __half2 h1 = __floats2half2_rn(v.z, v.w);
    ((__half2*)xh)[2 * i]     = h0;
    ((__half2*)xh)[2 * i + 1] = h1;
  }
}

__global__ void swiglu_kernel(const __half* __restrict__ g,
                              const __half* __restrict__ u,
                              __half* __restrict__ h, int n2) {
  int i = blockIdx.x * blockDim.x + threadIdx.x;
  if (i < n2) {
    float2 gf = __half22float2(((const __half2*)g)[i]);
    float2 uf = __half22float2(((const __half2*)u)[i]);
    float h0 = gf.x / (1.f + __expf(-gf.x)) * uf.x;
    float h1 = gf.y / (1.f + __expf(-gf.y)) * uf.y;
    ((__half2*)h)[i] = __floats2half2_rn(h0, h1);
  }
}

extern "C" void kernel_launch(void* const* d_in, const int* in_sizes, int n_in,
                              void* d_out, int out_size, void* d_ws, size_t ws_size,
                              hipStream_t stream)
{
  (void)in_sizes; (void)n_in; (void)ws_size;
  const float* x            = (const float*)d_in[0];
  const int*   gate_codes   = (const int*)d_in[1];
  const float* gate_absmax  = (const float*)d_in[2];
  const int*   up_codes     = (const int*)d_in[3];
  const float* up_absmax    = (const float*)d_in[4];
  const int*   down_codes   = (const int*)d_in[5];
  const float* down_absmax  = (const float*)d_in[6];
  float* out = (float*)d_out;

  // ws: xh 4MB | g 11.3MB | u 11.3MB  (h aliases g; total 26.6MB, same as R1)
  __half* xh = (__half*)d_ws;
  __half* g  = xh + (size_t)512 * 4096;
  __half* u  = g  + (size_t)512 * 11008;

  hipMemsetAsync(d_out, 0, (size_t)out_size * sizeof(float), stream);

  cast_f16_kernel<<<2048, 256, 0, stream>>>(x, xh, (512 * 4096) / 4);

  // gate+up fused dispatch: 2 Mtiles x 172 Ntiles x 2 mats = 688 blocks
  gemm_nf4<false><<<688, 256, 0, stream>>>(xh, gate_codes, gate_absmax,
                                           up_codes, up_absmax,
                                           g, u, nullptr,
                                           11008, 4096, 4096, 172);

  // h = silu(g) * u  (in place over g)
  swiglu_kernel<<<11008, 256, 0, stream>>>(g, u, g, (512 * 11008) / 2);

  // down: out += h * Wd^T, split-K=4: 2 x 64 x 4 = 512 blocks
  gemm_nf4<true><<<512, 256, 0, stream>>>(g, down_codes, down_absmax,
                                          nullptr, nullptr, nullptr, nullptr,
                                          out, 4096, 11008, 2752, 64);
}